// Round 9
// baseline (53.027 us; speedup 1.0000x reference)
//
#include <hip/hip_runtime.h>

// ConditionalDense: out[b,u] = sum_d x[b,d]*kernel[cls[b],d,u] + bias[cls[b],u]
// B=2048, D=512, U=512, C=100, all float32.
// R8: retile R7's proven structure for less traffic + better CU fill:
//   S_CHUNK 16->24 (logical W 190->119 MB), TU 256->128 (4 ytiles ->
//   ~476 blocks, 93% of 512 block-slots), PROWS=16 pieces of 8 KB ring-2.
//   LDS 64.1 KB -> still 2 blk/CU. x staged via global_load_lds (uniform
//   LDS dest per wave-instr = one x-row-half; per-lane global addr).
//   Balanced bijective XCD swizzle kept (R6 proved no-swizzle costs 25%;
//   same-class chunks g-adjacent -> same XCD -> L2 hits for 2nd chunk).

constexpr int C_CLS   = 100;
constexpr int B_N     = 2048;
constexpr int D_DIM   = 512;
constexpr int U_DIM   = 512;
constexpr int S_CHUNK = 24;     // samples per chunk
constexpr int MAX_CHUNKS = 184; // >= worst case 2048/24 + 100*23/24 = 182
constexpr int TU      = 128;    // u-columns per block (lane owns 2 u)
constexpr int PROWS   = 16;     // d-rows per staged W piece (8 KB)
constexpr int PIECES  = D_DIM / PROWS;   // 32
constexpr int NWG     = 4 * MAX_CHUNKS;  // 736 = 8*92

// ---------------- fused sort kernel (single block, 1024 threads) ----------------

__global__ void k_sort(const int* __restrict__ cls, int* __restrict__ order,
                       int* __restrict__ total_chunks, int* __restrict__ chunk_cls,
                       int* __restrict__ chunk_start, int* __restrict__ chunk_len) {
    __shared__ int s_cnt[128], s_off[128], s_chk[128], s_cur[128], s_base[128];
    int tid = threadIdx.x;
    if (tid < 128) s_cnt[tid] = 0;
    __syncthreads();
    for (int i = tid; i < B_N; i += 1024) atomicAdd(&s_cnt[cls[i]], 1);
    __syncthreads();
    int cnt = 0, nch = 0;
    if (tid < 128) {
        cnt = (tid < C_CLS) ? s_cnt[tid] : 0;
        nch = (cnt + S_CHUNK - 1) / S_CHUNK;
        s_off[tid] = cnt; s_chk[tid] = nch;
    }
    __syncthreads();
    for (int st = 1; st < 128; st <<= 1) {   // Hillis-Steele inclusive scan
        int a = 0, b = 0;
        if (tid >= st && tid < 128) { a = s_off[tid - st]; b = s_chk[tid - st]; }
        __syncthreads();
        if (tid < 128) { s_off[tid] += a; s_chk[tid] += b; }
        __syncthreads();
    }
    if (tid < C_CLS) {
        int off = s_off[tid] - cnt;   // exclusive prefix of counts
        int cb  = s_chk[tid] - nch;   // exclusive prefix of chunk counts
        s_base[tid] = off;
        s_cur[tid]  = 0;
        for (int j = 0; j < nch; ++j) {
            chunk_cls[cb + j]   = tid;
            chunk_start[cb + j] = off + j * S_CHUNK;
            chunk_len[cb + j]   = min(S_CHUNK, cnt - j * S_CHUNK);
        }
    }
    if (tid == 127) *total_chunks = s_chk[127];
    __syncthreads();
    for (int i = tid; i < B_N; i += 1024) {
        int c = cls[i];
        int p = atomicAdd(&s_cur[c], 1);
        order[s_base[c] + p] = i;
    }
}

// ---------------- main kernel ----------------
// Block = (chunk, ytile): 24 samples x 128 u-cols x full D=512.
// 256 thr / 4 waves; wave wv owns samples 6wv..6wv+5; lane owns u-pair
// u0 + 2*lane. W pieces (16x128 f32 = 8 KB) DMA'd via global_load_lds
// into ring-2 LDS (2 loads/thread/piece); x rows DMA'd into xs.
// LDS 64.1 KB -> 2 blocks/CU.

#define ISSUE(pi, qq) do {                                                    \
    const int db_ = (pi) * PROWS;                                             \
    _Pragma("unroll")                                                         \
    for (int j_ = 0; j_ < 2; ++j_) {                                          \
        const int rbase_ = wv * 4 + 2 * j_;          /* uniform per wave */   \
        const int r_ = rbase_ + (lane >> 5);         /* per-lane row */       \
        const float* gp_ = Wg + (size_t)(db_ + r_) * U_DIM + (lane & 31) * 4; \
        __builtin_amdgcn_global_load_lds(                                     \
            (const __attribute__((address_space(1))) void*)gp_,               \
            (__attribute__((address_space(3))) void*)&wbuf[qq][rbase_][0],    \
            16, 0, 0);                                                        \
    }                                                                         \
} while (0)

// x staging: wave wv stages rows 6wv..6wv+5, halves h=0,1 -> 12 instrs.
// All 64 lanes of one instr read the SAME x row (per-lane addr = base+4*lane)
// into the uniform LDS dest &xs[s][h*128] (1024 B linear).
#define ISSUE_X() do {                                                        \
    _Pragma("unroll")                                                         \
    for (int j_ = 0; j_ < 12; ++j_) {                                         \
        const int s_ = wv * 6 + (j_ >> 1);                                    \
        const int h_ = j_ & 1;                                                \
        int b_ = sidx[s_]; if (b_ < 0) b_ = sidx[0];  /* pad: clamp, junk */  \
        const float* gp_ = x + (size_t)b_ * D_DIM + h_ * 256 + lane * 4;      \
        __builtin_amdgcn_global_load_lds(                                     \
            (const __attribute__((address_space(1))) void*)gp_,               \
            (__attribute__((address_space(3))) void*)&xs[s_][h_ * 256],       \
            16, 0, 0);                                                        \
    }                                                                         \
} while (0)

#define COMPUTE(pi, qq) do {                                                  \
    const int dbase_ = (pi) * PROWS;                                          \
    _Pragma("unroll")                                                         \
    for (int g4 = 0; g4 < PROWS / 4; ++g4) {                                  \
        float2 w0 = *reinterpret_cast<const float2*>(&wbuf[qq][4*g4+0][2*lane]); \
        float2 w1 = *reinterpret_cast<const float2*>(&wbuf[qq][4*g4+1][2*lane]); \
        float2 w2 = *reinterpret_cast<const float2*>(&wbuf[qq][4*g4+2][2*lane]); \
        float2 w3 = *reinterpret_cast<const float2*>(&wbuf[qq][4*g4+3][2*lane]); \
        _Pragma("unroll")                                                     \
        for (int k = 0; k < 6; ++k) {                                         \
            float4 xq = *reinterpret_cast<const float4*>(&xs[6*wv + k][dbase_ + 4*g4]); \
            acc[k].x = fmaf(xq.x, w0.x, acc[k].x);                            \
            acc[k].x = fmaf(xq.y, w1.x, acc[k].x);                            \
            acc[k].x = fmaf(xq.z, w2.x, acc[k].x);                            \
            acc[k].x = fmaf(xq.w, w3.x, acc[k].x);                            \
            acc[k].y = fmaf(xq.x, w0.y, acc[k].y);                            \
            acc[k].y = fmaf(xq.y, w1.y, acc[k].y);                            \
            acc[k].y = fmaf(xq.z, w2.y, acc[k].y);                            \
            acc[k].y = fmaf(xq.w, w3.y, acc[k].y);                            \
        }                                                                     \
    }                                                                         \
} while (0)

// Wait piece pi landed (NCNT loads may stay outstanding), barrier, compute,
// barrier, refill the freed ring slot with piece pi+2.
#define STEP(pi, qq, NCNT) do {                                               \
    asm volatile("s_waitcnt vmcnt(" #NCNT ")" ::: "memory");                  \
    __builtin_amdgcn_s_barrier();                                             \
    COMPUTE(pi, qq);                                                          \
    asm volatile("" ::: "memory");                                            \
    __builtin_amdgcn_s_barrier();                                             \
    if ((pi) + 2 < PIECES) ISSUE((pi) + 2, qq);                               \
} while (0)

__launch_bounds__(256, 2)
__global__ void k_main(const float* __restrict__ x, const float* __restrict__ kern,
                       const float* __restrict__ bias, const int* __restrict__ order,
                       const int* __restrict__ total_chunks,
                       const int* __restrict__ chunk_cls,
                       const int* __restrict__ chunk_start,
                       const int* __restrict__ chunk_len,
                       float* __restrict__ out) {
    // Runtime-balanced bijective XCD swizzle over active count A = 4*tc.
    // Consecutive g (one chunk's 4 ytiles; same class's chunks) -> one XCD.
    int tc = *total_chunks;
    int A  = 4 * tc;
    int xc = blockIdx.x & 7;
    int ii = blockIdx.x >> 3;           // [0, 92)
    int q  = A >> 3, r = A & 7;
    int mycnt = (xc < r) ? (q + 1) : q;
    if (ii >= mycnt) return;            // block-uniform exit (before barriers)
    int g = ((xc < r) ? xc * (q + 1) : r * (q + 1) + (xc - r) * q) + ii;

    int chunk = g >> 2;
    int ytile = g & 3;

    int tid  = threadIdx.x;
    int lane = tid & 63;
    int wv   = tid >> 6;

    int c     = chunk_cls[chunk];
    int start = chunk_start[chunk];
    int len   = chunk_len[chunk];
    int u0    = ytile * TU;

    __shared__ float wbuf[2][PROWS][TU];   // 16 KB
    __shared__ float xs[S_CHUNK][D_DIM];   // 48 KB
    __shared__ int   sidx[S_CHUNK];        // -> 64.1 KB, 2 blocks/CU

    const float* Wg = kern + (size_t)c * (D_DIM * U_DIM) + u0;

    // ---- prologue: sidx first (ISSUE_X needs it), then all DMA ----
    if (tid < S_CHUNK) sidx[tid] = (tid < len) ? order[start + tid] : -1;
    asm volatile("s_waitcnt lgkmcnt(0)" ::: "memory");
    __builtin_amdgcn_s_barrier();          // sidx visible

    ISSUE_X();                             // 12 loads/thread: xs rows
    ISSUE(0, 0);                           // 2 loads/thread: W piece 0
    ISSUE(1, 1);                           // 2 loads/thread: W piece 1

    float2 acc[6];
    #pragma unroll
    for (int k = 0; k < 6; ++k) acc[k] = make_float2(0.f, 0.f);

    // ---- main loop: 32 pieces, ring-2. STEP(0)'s vmcnt(2) also drains x
    // (x's 12 + piece0's 2 are the oldest 14 of 16 outstanding). Steady:
    // piece i landed, piece i+1 (2 loads) in flight during compute.
    #pragma unroll 1
    for (int i = 0; i < PIECES - 2; i += 2) {   // pieces 0..29
        STEP(i,     0, 2);
        STEP(i + 1, 1, 2);
    }
    STEP(PIECES - 2, 0, 2);                // piece 30 (31 in flight)
    STEP(PIECES - 1, 1, 0);                // piece 31

    // ---- epilogue: direct stores, one writer per output element ----
    float2 bb = *reinterpret_cast<const float2*>(&bias[c * U_DIM + u0 + 2 * lane]);
    #pragma unroll
    for (int k = 0; k < 6; ++k) {
        int b = sidx[6 * wv + k];
        if (b >= 0) {
            float2 o = make_float2(acc[k].x + bb.x, acc[k].y + bb.y);
            *reinterpret_cast<float2*>(&out[(size_t)b * U_DIM + u0 + 2 * lane]) = o;
        }
    }
}

// ---------------- launch ----------------

extern "C" void kernel_launch(void* const* d_in, const int* in_sizes, int n_in,
                              void* d_out, int out_size, void* d_ws, size_t ws_size,
                              hipStream_t stream) {
    const float* x    = (const float*)d_in[0];
    const int*   cls  = (const int*)d_in[1];
    const float* kern = (const float*)d_in[2];
    const float* bias = (const float*)d_in[3];
    float*       out  = (float*)d_out;

    int* ws           = (int*)d_ws;
    int* order        = ws;          // 2048
    int* total_chunks = ws + 2048;   // 1
    int* chunk_cls    = ws + 2112;   // 184
    int* chunk_start  = ws + 2304;   // 184
    int* chunk_len    = ws + 2496;   // 184

    hipLaunchKernelGGL(k_sort, dim3(1), dim3(1024), 0, stream,
                       cls, order, total_chunks, chunk_cls, chunk_start, chunk_len);
    hipLaunchKernelGGL(k_main, dim3(NWG), dim3(256), 0, stream,
                       x, kern, bias, order, total_chunks, chunk_cls, chunk_start, chunk_len, out);
}

// Round 10
// 51.690 us; speedup vs baseline: 1.0259x; 1.0259x over previous
//
#include <hip/hip_runtime.h>

// ConditionalDense: out[b,u] = sum_d x[b,d]*kernel[cls[b],d,u] + bias[cls[b],u]
// B=2048, D=512, U=512, C=100, all float32.
// R9 = R7 tile (S=16, TU=256, 16 KB W pieces) + ring-3 wbuf: 2 pieces
// (32 KB/block) in flight during every compute step (R7/R8 A/B proved
// DMA rate ∝ bytes-in-flight). To fit 2 blk/CU, xs holds one 256-col
// d-half (16 KB) and is restaged once at the piece-15/16 boundary via
// interleaved issue (no full drain). LDS 64.1 KB.

constexpr int C_CLS   = 100;
constexpr int B_N     = 2048;
constexpr int D_DIM   = 512;
constexpr int U_DIM   = 512;
constexpr int S_CHUNK = 16;     // samples per chunk
constexpr int MAX_CHUNKS = 228; // >= worst case 2048/16 + 100 = 228
constexpr int TU      = 256;    // u-columns per block
constexpr int PROWS   = 16;     // d-rows per staged W piece (16 KB)
constexpr int PIECES  = D_DIM / PROWS;   // 32
constexpr int XCOLS   = 256;    // xs holds one d-half
constexpr int NWG     = 2 * MAX_CHUNKS;  // 456

// ---------------- fused sort kernel (single block, 1024 threads) ----------------

__global__ void k_sort(const int* __restrict__ cls, int* __restrict__ order,
                       int* __restrict__ total_chunks, int* __restrict__ chunk_cls,
                       int* __restrict__ chunk_start, int* __restrict__ chunk_len) {
    __shared__ int s_cnt[128], s_off[128], s_chk[128], s_cur[128], s_base[128];
    int tid = threadIdx.x;
    if (tid < 128) s_cnt[tid] = 0;
    __syncthreads();
    for (int i = tid; i < B_N; i += 1024) atomicAdd(&s_cnt[cls[i]], 1);
    __syncthreads();
    int cnt = 0, nch = 0;
    if (tid < 128) {
        cnt = (tid < C_CLS) ? s_cnt[tid] : 0;
        nch = (cnt + S_CHUNK - 1) / S_CHUNK;
        s_off[tid] = cnt; s_chk[tid] = nch;
    }
    __syncthreads();
    for (int st = 1; st < 128; st <<= 1) {   // Hillis-Steele inclusive scan
        int a = 0, b = 0;
        if (tid >= st && tid < 128) { a = s_off[tid - st]; b = s_chk[tid - st]; }
        __syncthreads();
        if (tid < 128) { s_off[tid] += a; s_chk[tid] += b; }
        __syncthreads();
    }
    if (tid < C_CLS) {
        int off = s_off[tid] - cnt;   // exclusive prefix of counts
        int cb  = s_chk[tid] - nch;   // exclusive prefix of chunk counts
        s_base[tid] = off;
        s_cur[tid]  = 0;
        for (int j = 0; j < nch; ++j) {
            chunk_cls[cb + j]   = tid;
            chunk_start[cb + j] = off + j * S_CHUNK;
            chunk_len[cb + j]   = min(S_CHUNK, cnt - j * S_CHUNK);
        }
    }
    if (tid == 127) *total_chunks = s_chk[127];
    __syncthreads();
    for (int i = tid; i < B_N; i += 1024) {
        int c = cls[i];
        int p = atomicAdd(&s_cur[c], 1);
        order[s_base[c] + p] = i;
    }
}

// ---------------- main kernel ----------------
// Block = (chunk, ytile): 16 samples x 256 u-cols x full D=512.
// 256 thr / 4 waves; wave wv owns samples 4wv..4wv+3; lane owns 4 u.
// wbuf: ring-3 of 16x256 f32 W pieces (48 KB); xs: 16x256 f32 d-half (16 KB).

#define ISSUE(pi) do {                                                        \
    const int q_ = (pi) % 3; const int db_ = (pi) * PROWS;                    \
    _Pragma("unroll")                                                         \
    for (int j_ = 0; j_ < 4; ++j_) {                                          \
        const int r_ = wv * 4 + j_;                                           \
        const float* gp_ = Wg + (size_t)(db_ + r_) * U_DIM + lane * 4;        \
        __builtin_amdgcn_global_load_lds(                                     \
            (const __attribute__((address_space(1))) void*)gp_,               \
            (__attribute__((address_space(3))) void*)&wbuf[q_][r_][0],        \
            16, 0, 0);                                                        \
    }                                                                         \
} while (0)

// Stage xs = x[:, h*256 : h*256+256]; 4 instrs/thread, each instr = one
// full 256-f32 row (uniform LDS dest, per-lane global addr).
#define ISSUE_XH(h) do {                                                      \
    _Pragma("unroll")                                                         \
    for (int j_ = 0; j_ < 4; ++j_) {                                          \
        const int s_ = wv * 4 + j_;                                           \
        int b_ = sidx[s_]; if (b_ < 0) b_ = sidx[0];  /* pad: clamp, junk */  \
        const float* gp_ = x + (size_t)b_ * D_DIM + (h) * XCOLS + lane * 4;   \
        __builtin_amdgcn_global_load_lds(                                     \
            (const __attribute__((address_space(1))) void*)gp_,               \
            (__attribute__((address_space(3))) void*)&xs[s_][0],              \
            16, 0, 0);                                                        \
    }                                                                         \
} while (0)

#define COMPUTE(pi) do {                                                      \
    const int q_ = (pi) % 3;                                                  \
    const int lb_ = ((pi) & (PIECES / 2 - 1)) * PROWS;  /* col base in xs */  \
    _Pragma("unroll")                                                         \
    for (int g4 = 0; g4 < PROWS / 4; ++g4) {                                  \
        float4 w0 = *reinterpret_cast<const float4*>(&wbuf[q_][4*g4+0][lane*4]); \
        float4 w1 = *reinterpret_cast<const float4*>(&wbuf[q_][4*g4+1][lane*4]); \
        float4 w2 = *reinterpret_cast<const float4*>(&wbuf[q_][4*g4+2][lane*4]); \
        float4 w3 = *reinterpret_cast<const float4*>(&wbuf[q_][4*g4+3][lane*4]); \
        _Pragma("unroll")                                                     \
        for (int k = 0; k < 4; ++k) {                                         \
            float4 xq = *reinterpret_cast<const float4*>(&xs[4*wv + k][lb_ + 4*g4]); \
            acc[k].x = fmaf(xq.x, w0.x, acc[k].x);                            \
            acc[k].x = fmaf(xq.y, w1.x, acc[k].x);                            \
            acc[k].x = fmaf(xq.z, w2.x, acc[k].x);                            \
            acc[k].x = fmaf(xq.w, w3.x, acc[k].x);                            \
            acc[k].y = fmaf(xq.x, w0.y, acc[k].y);                            \
            acc[k].y = fmaf(xq.y, w1.y, acc[k].y);                            \
            acc[k].y = fmaf(xq.z, w2.y, acc[k].y);                            \
            acc[k].y = fmaf(xq.w, w3.y, acc[k].y);                            \
            acc[k].z = fmaf(xq.x, w0.z, acc[k].z);                            \
            acc[k].z = fmaf(xq.y, w1.z, acc[k].z);                            \
            acc[k].z = fmaf(xq.z, w2.z, acc[k].z);                            \
            acc[k].z = fmaf(xq.w, w3.z, acc[k].z);                            \
            acc[k].w = fmaf(xq.x, w0.w, acc[k].w);                            \
            acc[k].w = fmaf(xq.y, w1.w, acc[k].w);                            \
            acc[k].w = fmaf(xq.z, w2.w, acc[k].w);                            \
            acc[k].w = fmaf(xq.w, w3.w, acc[k].w);                            \
        }                                                                     \
    }                                                                         \
} while (0)

// Standard step: wait (NCNT instrs may stay outstanding), compute piece pi,
// then refill the slot just freed with piece pi+3 (ring-3: 2 pieces stay
// in flight through the whole compute).
#define STEP(pi, NCNT) do {                                                   \
    asm volatile("s_waitcnt vmcnt(" #NCNT ")" ::: "memory");                  \
    __builtin_amdgcn_s_barrier();                                             \
    COMPUTE(pi);                                                              \
    asm volatile("" ::: "memory");                                            \
    __builtin_amdgcn_s_barrier();                                             \
    if ((pi) + 3 < PIECES) ISSUE((pi) + 3);                                   \
} while (0)

__launch_bounds__(256, 2)
__global__ void k_main(const float* __restrict__ x, const float* __restrict__ kern,
                       const float* __restrict__ bias, const int* __restrict__ order,
                       const int* __restrict__ total_chunks,
                       const int* __restrict__ chunk_cls,
                       const int* __restrict__ chunk_start,
                       const int* __restrict__ chunk_len,
                       float* __restrict__ out) {
    // Runtime-balanced bijective XCD swizzle over active count A = 2*tc
    // (R6 proved swizzle-off costs ~25%; R7/R8 proved flavor is free).
    int tc = *total_chunks;
    int A  = 2 * tc;
    int xc = blockIdx.x & 7;
    int ii = blockIdx.x >> 3;
    int q  = A >> 3, r = A & 7;
    int mycnt = (xc < r) ? (q + 1) : q;
    if (ii >= mycnt) return;            // block-uniform exit (before barriers)
    int g = ((xc < r) ? xc * (q + 1) : r * (q + 1) + (xc - r) * q) + ii;

    int chunk = g >> 1;
    int ytile = g & 1;

    int tid  = threadIdx.x;
    int lane = tid & 63;
    int wv   = tid >> 6;

    int c     = chunk_cls[chunk];
    int start = chunk_start[chunk];
    int len   = chunk_len[chunk];
    int u0    = ytile * TU;

    __shared__ float wbuf[3][PROWS][TU];   // 48 KB, ring-3
    __shared__ float xs[S_CHUNK][XCOLS];   // 16 KB, one d-half
    __shared__ int   sidx[S_CHUNK];        // -> 64.1 KB, 2 blocks/CU

    const float* Wg = kern + (size_t)c * (D_DIM * U_DIM) + u0;

    // ---- prologue: sidx, then x half 0 + W pieces 0..2 (16 instrs) ----
    if (tid < S_CHUNK) sidx[tid] = (tid < len) ? order[start + tid] : -1;
    asm volatile("s_waitcnt lgkmcnt(0)" ::: "memory");
    __builtin_amdgcn_s_barrier();          // sidx visible

    ISSUE_XH(0);                           // 4 instrs (oldest)
    ISSUE(0);                              // 4
    ISSUE(1);                              // 4
    ISSUE(2);                              // 4   -> 16 outstanding

    float4 acc[4];
    #pragma unroll
    for (int k = 0; k < 4; ++k) acc[k] = make_float4(0.f, 0.f, 0.f, 0.f);

    // ---- steps 0..14: steady ring-3, xs half 0.
    // step 0 wait vmcnt(8): drains x(4)+W0(4); W1,W2 stay in flight.
    STEP(0, 8);
    #pragma unroll 1
    for (int i = 1; i <= 14; ++i) STEP(i, 8);

    // ---- step 15 + x restage (interleaved issue, no full drain) ----
    asm volatile("s_waitcnt vmcnt(8)" ::: "memory");   // W15 landed
    __builtin_amdgcn_s_barrier();
    COMPUTE(15);
    asm volatile("" ::: "memory");
    __builtin_amdgcn_s_barrier();          // all waves done with xs half 0
    ISSUE_XH(1);                           // overwrite xs with half 1
    ISSUE(18);                             // outstanding: W16,W17,X1,W18

    // ---- step 16: wait W16 + X1 -> vmcnt(4) (W18 stays in flight) ----
    asm volatile("s_waitcnt vmcnt(4)" ::: "memory");
    __builtin_amdgcn_s_barrier();
    COMPUTE(16);
    asm volatile("" ::: "memory");
    __builtin_amdgcn_s_barrier();
    ISSUE(19);                             // outstanding: W18,W19

    // ---- steps 17..29: steady (W17 already landed; vmcnt(8) passes) ----
    #pragma unroll 1
    for (int i = 17; i <= 29; ++i) STEP(i, 8);

    // ---- tail ----
    STEP(30, 4);                           // W31 stays in flight
    STEP(31, 0);

    // ---- epilogue: direct stores, one writer per output element ----
    float4 bb = *reinterpret_cast<const float4*>(&bias[c * U_DIM + u0 + lane * 4]);
    #pragma unroll
    for (int k = 0; k < 4; ++k) {
        int b = sidx[4 * wv + k];
        if (b >= 0) {
            float4 o = make_float4(acc[k].x + bb.x, acc[k].y + bb.y,
                                   acc[k].z + bb.z, acc[k].w + bb.w);
            *reinterpret_cast<float4*>(&out[(size_t)b * U_DIM + u0 + lane * 4]) = o;
        }
    }
}

// ---------------- launch ----------------

extern "C" void kernel_launch(void* const* d_in, const int* in_sizes, int n_in,
                              void* d_out, int out_size, void* d_ws, size_t ws_size,
                              hipStream_t stream) {
    const float* x    = (const float*)d_in[0];
    const int*   cls  = (const int*)d_in[1];
    const float* kern = (const float*)d_in[2];
    const float* bias = (const float*)d_in[3];
    float*       out  = (float*)d_out;

    int* ws           = (int*)d_ws;
    int* order        = ws;          // 2048
    int* total_chunks = ws + 2048;   // 1
    int* chunk_cls    = ws + 2112;   // 228
    int* chunk_start  = ws + 2368;   // 228
    int* chunk_len    = ws + 2624;   // 228

    hipLaunchKernelGGL(k_sort, dim3(1), dim3(1024), 0, stream,
                       cls, order, total_chunks, chunk_cls, chunk_start, chunk_len);
    hipLaunchKernelGGL(k_main, dim3(NWG), dim3(256), 0, stream,
                       x, kern, bias, order, total_chunks, chunk_cls, chunk_start, chunk_len, out);
}

// Round 11
// 41.732 us; speedup vs baseline: 1.2706x; 1.2386x over previous
//
#include <hip/hip_runtime.h>

// ConditionalDense: out[b,u] = sum_d x[b,d]*kernel[cls[b],d,u] + bias[cls[b],u]
// B=2048, D=512, U=512, C=100, all float32.
// R10 = R7 per-thread structure EXACTLY (4 samples x 4 u per thread, 16 KB
// W pieces, ring-2, steady counted vmcnt, reg-path x staging, balanced XCD
// swizzle), but each (chunk,ytile) is split into TWO 8-sample blocks of
// 128 threads (2 waves). Doubles active blocks 380 -> ~760 and drops LDS
// to 48.2 KB -> 3 blocks/CU, fixing R7's 1.48 avg residency (half the CUs
// ran one block = exposed latency, the R4 failure mode). W logically read
// 2x, but sibling block is g-adjacent -> same XCD -> L2-served duplicate.

constexpr int C_CLS   = 100;
constexpr int B_N     = 2048;
constexpr int D_DIM   = 512;
constexpr int U_DIM   = 512;
constexpr int S_CHUNK = 16;     // samples per chunk (sort granularity)
constexpr int SB      = 8;      // samples per BLOCK (chunk half)
constexpr int MAX_CHUNKS = 228; // >= worst case 2048/16 + 100 = 228
constexpr int TU      = 256;    // u-columns per block
constexpr int PROWS   = 16;     // d-rows per staged W piece (16 KB)
constexpr int PIECES  = D_DIM / PROWS;   // 32
constexpr int NWG     = 4 * MAX_CHUNKS;  // 912 = 8*114

// ---------------- fused sort kernel (single block, 1024 threads) ----------------

__global__ void k_sort(const int* __restrict__ cls, int* __restrict__ order,
                       int* __restrict__ total_chunks, int* __restrict__ chunk_cls,
                       int* __restrict__ chunk_start, int* __restrict__ chunk_len) {
    __shared__ int s_cnt[128], s_off[128], s_chk[128], s_cur[128], s_base[128];
    int tid = threadIdx.x;
    if (tid < 128) s_cnt[tid] = 0;
    __syncthreads();
    for (int i = tid; i < B_N; i += 1024) atomicAdd(&s_cnt[cls[i]], 1);
    __syncthreads();
    int cnt = 0, nch = 0;
    if (tid < 128) {
        cnt = (tid < C_CLS) ? s_cnt[tid] : 0;
        nch = (cnt + S_CHUNK - 1) / S_CHUNK;
        s_off[tid] = cnt; s_chk[tid] = nch;
    }
    __syncthreads();
    for (int st = 1; st < 128; st <<= 1) {   // Hillis-Steele inclusive scan
        int a = 0, b = 0;
        if (tid >= st && tid < 128) { a = s_off[tid - st]; b = s_chk[tid - st]; }
        __syncthreads();
        if (tid < 128) { s_off[tid] += a; s_chk[tid] += b; }
        __syncthreads();
    }
    if (tid < C_CLS) {
        int off = s_off[tid] - cnt;   // exclusive prefix of counts
        int cb  = s_chk[tid] - nch;   // exclusive prefix of chunk counts
        s_base[tid] = off;
        s_cur[tid]  = 0;
        for (int j = 0; j < nch; ++j) {
            chunk_cls[cb + j]   = tid;
            chunk_start[cb + j] = off + j * S_CHUNK;
            chunk_len[cb + j]   = min(S_CHUNK, cnt - j * S_CHUNK);
        }
    }
    if (tid == 127) *total_chunks = s_chk[127];
    __syncthreads();
    for (int i = tid; i < B_N; i += 1024) {
        int c = cls[i];
        int p = atomicAdd(&s_cur[c], 1);
        order[s_base[c] + p] = i;
    }
}

// ---------------- main kernel ----------------
// Block = (chunk, ytile, shalf): 8 samples x 256 u-cols x full D=512.
// 128 thr / 2 waves; wave wv owns samples 4wv..4wv+3 (of the block's 8);
// lane owns u = u0 + lane*4. W pieces (16x256 f32 = 16 KB) DMA'd via
// global_load_lds into ring-2 LDS: 16 instrs/piece / 2 waves = 8 per wave.
// LDS 48.2 KB -> 3 blocks/CU.

#define ISSUE(pi, qq) do {                                                    \
    const int db_ = (pi) * PROWS;                                             \
    _Pragma("unroll")                                                         \
    for (int j_ = 0; j_ < 8; ++j_) {                                          \
        const int r_ = wv * 8 + j_;                                           \
        const float* gp_ = Wg + (size_t)(db_ + r_) * U_DIM + lane * 4;        \
        __builtin_amdgcn_global_load_lds(                                     \
            (const __attribute__((address_space(1))) void*)gp_,               \
            (__attribute__((address_space(3))) void*)&wbuf[qq][r_][0],        \
            16, 0, 0);                                                        \
    }                                                                         \
} while (0)

#define COMPUTE(pi, qq) do {                                                  \
    const int dbase_ = (pi) * PROWS;                                          \
    _Pragma("unroll")                                                         \
    for (int g4 = 0; g4 < PROWS / 4; ++g4) {                                  \
        float4 w0 = *reinterpret_cast<const float4*>(&wbuf[qq][4*g4+0][lane*4]); \
        float4 w1 = *reinterpret_cast<const float4*>(&wbuf[qq][4*g4+1][lane*4]); \
        float4 w2 = *reinterpret_cast<const float4*>(&wbuf[qq][4*g4+2][lane*4]); \
        float4 w3 = *reinterpret_cast<const float4*>(&wbuf[qq][4*g4+3][lane*4]); \
        _Pragma("unroll")                                                     \
        for (int k = 0; k < 4; ++k) {                                         \
            float4 xq = *reinterpret_cast<const float4*>(&xs[4*wv + k][dbase_ + 4*g4]); \
            acc[k].x = fmaf(xq.x, w0.x, acc[k].x);                            \
            acc[k].x = fmaf(xq.y, w1.x, acc[k].x);                            \
            acc[k].x = fmaf(xq.z, w2.x, acc[k].x);                            \
            acc[k].x = fmaf(xq.w, w3.x, acc[k].x);                            \
            acc[k].y = fmaf(xq.x, w0.y, acc[k].y);                            \
            acc[k].y = fmaf(xq.y, w1.y, acc[k].y);                            \
            acc[k].y = fmaf(xq.z, w2.y, acc[k].y);                            \
            acc[k].y = fmaf(xq.w, w3.y, acc[k].y);                            \
            acc[k].z = fmaf(xq.x, w0.z, acc[k].z);                            \
            acc[k].z = fmaf(xq.y, w1.z, acc[k].z);                            \
            acc[k].z = fmaf(xq.z, w2.z, acc[k].z);                            \
            acc[k].z = fmaf(xq.w, w3.z, acc[k].z);                            \
            acc[k].w = fmaf(xq.x, w0.w, acc[k].w);                            \
            acc[k].w = fmaf(xq.y, w1.w, acc[k].w);                            \
            acc[k].w = fmaf(xq.z, w2.w, acc[k].w);                            \
            acc[k].w = fmaf(xq.w, w3.w, acc[k].w);                            \
        }                                                                     \
    }                                                                         \
} while (0)

__launch_bounds__(128)
__global__ void k_main(const float* __restrict__ x, const float* __restrict__ kern,
                       const float* __restrict__ bias, const int* __restrict__ order,
                       const int* __restrict__ total_chunks,
                       const int* __restrict__ chunk_cls,
                       const int* __restrict__ chunk_start,
                       const int* __restrict__ chunk_len,
                       float* __restrict__ out) {
    // Runtime-balanced bijective XCD swizzle over active count A = 4*tc.
    // Consecutive g (one chunk's 2 sample-halves, 2 ytiles; same-class
    // chunks) -> one XCD -> W duplicates served by that XCD's L2.
    int tc = *total_chunks;
    int A  = 4 * tc;
    int xc = blockIdx.x & 7;
    int ii = blockIdx.x >> 3;
    int q  = A >> 3, r = A & 7;
    int mycnt = (xc < r) ? (q + 1) : q;
    if (ii >= mycnt) return;            // block-uniform exit (before barriers)
    int g = ((xc < r) ? xc * (q + 1) : r * (q + 1) + (xc - r) * q) + ii;

    int chunk = g >> 2;
    int ytile = (g >> 1) & 1;
    int shalf = g & 1;

    int tid  = threadIdx.x;
    int lane = tid & 63;
    int wv   = tid >> 6;                // 0 or 1

    int c     = chunk_cls[chunk];
    int start = chunk_start[chunk];
    int len   = chunk_len[chunk];
    int u0    = ytile * TU;

    __shared__ float wbuf[2][PROWS][TU];   // 32 KB, ring-2
    __shared__ float xs[SB][D_DIM];        // 16 KB
    __shared__ int   sidx[SB];             // -> 48.2 KB, 3 blocks/CU

    const float* Wg = kern + (size_t)c * (D_DIM * U_DIM) + u0;

    // ---- prologue (R7-exact ordering): W pieces 0,1 first, then sidx + x ----
    ISSUE(0, 0);
    ISSUE(1, 1);
    if (tid < SB) {
        int sg = shalf * SB + tid;         // sample index within the chunk
        sidx[tid] = (sg < len) ? order[start + sg] : -1;
    }
    asm volatile("s_waitcnt lgkmcnt(0)" ::: "memory");
    __builtin_amdgcn_s_barrier();          // sidx visible

    float4 xv[8];
    #pragma unroll
    for (int j = 0; j < 8; ++j) {          // 8 rows x 128 float4 / 128 thr
        int i = tid + 128 * j;
        int s = i >> 7, f = i & 127;
        int b = sidx[s];
        xv[j] = make_float4(0.f, 0.f, 0.f, 0.f);
        if (b >= 0) xv[j] = reinterpret_cast<const float4*>(x)[b * (D_DIM / 4) + f];
    }
    asm volatile("s_waitcnt vmcnt(0)" ::: "memory");   // x loaded; pieces 0,1 landed
    #pragma unroll
    for (int j = 0; j < 8; ++j) {
        int i = tid + 128 * j;
        int s = i >> 7, f = i & 127;
        reinterpret_cast<float4*>(&xs[s][0])[f] = xv[j];
    }
    asm volatile("s_waitcnt lgkmcnt(0)" ::: "memory");
    __builtin_amdgcn_s_barrier();          // xs visible; pipeline primed

    float4 acc[4];
    #pragma unroll
    for (int k = 0; k < 4; ++k) acc[k] = make_float4(0.f, 0.f, 0.f, 0.f);

    // ---- main pipelined loop (R7 cadence; 8 loads/wave/piece -> vmcnt(8)) ----
    #pragma unroll 1
    for (int i = 0; i < PIECES; ++i) {
        if (i > 0) {
            if (i + 1 < PIECES) asm volatile("s_waitcnt vmcnt(8)" ::: "memory");
            else                asm volatile("s_waitcnt vmcnt(0)" ::: "memory");
        }
        __builtin_amdgcn_s_barrier();      // piece i fully in LDS
        COMPUTE(i, (i & 1));
        asm volatile("" ::: "memory");
        __builtin_amdgcn_s_barrier();      // all waves done reading buf[i&1]
        if (i + 2 < PIECES) ISSUE(i + 2, (i & 1));
    }

    // ---- epilogue: direct stores, one writer per output element ----
    float4 bb = *reinterpret_cast<const float4*>(&bias[c * U_DIM + u0 + lane * 4]);
    #pragma unroll
    for (int k = 0; k < 4; ++k) {
        int b = sidx[4 * wv + k];
        if (b >= 0) {
            float4 o = make_float4(acc[k].x + bb.x, acc[k].y + bb.y,
                                   acc[k].z + bb.z, acc[k].w + bb.w);
            *reinterpret_cast<float4*>(&out[(size_t)b * U_DIM + u0 + lane * 4]) = o;
        }
    }
}

// ---------------- launch ----------------

extern "C" void kernel_launch(void* const* d_in, const int* in_sizes, int n_in,
                              void* d_out, int out_size, void* d_ws, size_t ws_size,
                              hipStream_t stream) {
    const float* x    = (const float*)d_in[0];
    const int*   cls  = (const int*)d_in[1];
    const float* kern = (const float*)d_in[2];
    const float* bias = (const float*)d_in[3];
    float*       out  = (float*)d_out;

    int* ws           = (int*)d_ws;
    int* order        = ws;          // 2048
    int* total_chunks = ws + 2048;   // 1
    int* chunk_cls    = ws + 2112;   // 228
    int* chunk_start  = ws + 2368;   // 228
    int* chunk_len    = ws + 2624;   // 228

    hipLaunchKernelGGL(k_sort, dim3(1), dim3(1024), 0, stream,
                       cls, order, total_chunks, chunk_cls, chunk_start, chunk_len);
    hipLaunchKernelGGL(k_main, dim3(NWG), dim3(128), 0, stream,
                       x, kern, bias, order, total_chunks, chunk_cls, chunk_start, chunk_len, out);
}

// Round 12
// 41.067 us; speedup vs baseline: 1.2912x; 1.0162x over previous
//
#include <hip/hip_runtime.h>

// ConditionalDense: out[b,u] = sum_d x[b,d]*kernel[cls[b],d,u] + bias[cls[b],u]
// B=2048, D=512, U=512, C=100, all float32.
// R11: BARRIER-FREE main loop. Wave wv privately owns d-rows
// {16p+4wv..16p+4wv+3} of every piece p: it DMAs exactly those rows into
// its own wbuf slice and is the only reader -> no cross-wave hazard, no
// s_barrier in the 32-piece loop; each wave self-paces on per-wave counted
// vmcnt. acc[16 samples][4 u] partials per thread; one 4-wave LDS tree
// reduction at the end (reusing retired wbuf). Everything else = proven
// R7 envelope: S=16, TU=256, 16 KB pieces ring-2, reg-path x staging,
// balanced bijective XCD swizzle, LDS 64.3 KB -> 2 blocks/CU.

constexpr int C_CLS   = 100;
constexpr int B_N     = 2048;
constexpr int D_DIM   = 512;
constexpr int U_DIM   = 512;
constexpr int S_CHUNK = 16;     // samples per chunk
constexpr int MAX_CHUNKS = 228; // >= worst case 2048/16 + 100 = 228
constexpr int TU      = 256;    // u-columns per block
constexpr int PROWS   = 16;     // d-rows per piece (16 KB)
constexpr int PIECES  = D_DIM / PROWS;   // 32
constexpr int NWG     = 2 * MAX_CHUNKS;  // 456

// ---------------- fused sort kernel (single block, 1024 threads) ----------------

__global__ void k_sort(const int* __restrict__ cls, int* __restrict__ order,
                       int* __restrict__ total_chunks, int* __restrict__ chunk_cls,
                       int* __restrict__ chunk_start, int* __restrict__ chunk_len) {
    __shared__ int s_cnt[128], s_off[128], s_chk[128], s_cur[128], s_base[128];
    int tid = threadIdx.x;
    if (tid < 128) s_cnt[tid] = 0;
    __syncthreads();
    for (int i = tid; i < B_N; i += 1024) atomicAdd(&s_cnt[cls[i]], 1);
    __syncthreads();
    int cnt = 0, nch = 0;
    if (tid < 128) {
        cnt = (tid < C_CLS) ? s_cnt[tid] : 0;
        nch = (cnt + S_CHUNK - 1) / S_CHUNK;
        s_off[tid] = cnt; s_chk[tid] = nch;
    }
    __syncthreads();
    for (int st = 1; st < 128; st <<= 1) {   // Hillis-Steele inclusive scan
        int a = 0, b = 0;
        if (tid >= st && tid < 128) { a = s_off[tid - st]; b = s_chk[tid - st]; }
        __syncthreads();
        if (tid < 128) { s_off[tid] += a; s_chk[tid] += b; }
        __syncthreads();
    }
    if (tid < C_CLS) {
        int off = s_off[tid] - cnt;   // exclusive prefix of counts
        int cb  = s_chk[tid] - nch;   // exclusive prefix of chunk counts
        s_base[tid] = off;
        s_cur[tid]  = 0;
        for (int j = 0; j < nch; ++j) {
            chunk_cls[cb + j]   = tid;
            chunk_start[cb + j] = off + j * S_CHUNK;
            chunk_len[cb + j]   = min(S_CHUNK, cnt - j * S_CHUNK);
        }
    }
    if (tid == 127) *total_chunks = s_chk[127];
    __syncthreads();
    for (int i = tid; i < B_N; i += 1024) {
        int c = cls[i];
        int p = atomicAdd(&s_cur[c], 1);
        order[s_base[c] + p] = i;
    }
}

// ---------------- main kernel ----------------
// Block = (chunk, ytile): 16 samples x 256 u-cols x full D=512, 256 thr /
// 4 waves. Wave wv: d-rows 4wv..4wv+3 (mod 16) of each piece, ALL samples.
// Thread: acc[16 samples] float4 (4 u). No main-loop barriers.

#define ISSUE(pi, qq) do {                                                    \
    const int db_ = (pi) * PROWS;                                             \
    _Pragma("unroll")                                                         \
    for (int j_ = 0; j_ < 4; ++j_) {                                          \
        const int r_ = 4 * wv + j_;                                           \
        const float* gp_ = Wg + (size_t)(db_ + r_) * U_DIM + lane * 4;        \
        __builtin_amdgcn_global_load_lds(                                     \
            (const __attribute__((address_space(1))) void*)gp_,               \
            (__attribute__((address_space(3))) void*)&wbuf[qq][r_][0],        \
            16, 0, 0);                                                        \
    }                                                                         \
} while (0)

#define COMPUTE(pi, qq) do {                                                  \
    const int dcol_ = (pi) * PROWS + 4 * wv;                                  \
    float4 w0 = *reinterpret_cast<const float4*>(&wbuf[qq][4*wv+0][lane*4]);  \
    float4 w1 = *reinterpret_cast<const float4*>(&wbuf[qq][4*wv+1][lane*4]);  \
    float4 w2 = *reinterpret_cast<const float4*>(&wbuf[qq][4*wv+2][lane*4]);  \
    float4 w3 = *reinterpret_cast<const float4*>(&wbuf[qq][4*wv+3][lane*4]);  \
    _Pragma("unroll")                                                         \
    for (int s = 0; s < S_CHUNK; ++s) {                                       \
        float4 xq = *reinterpret_cast<const float4*>(&xs[s][dcol_]);          \
        acc[s].x = fmaf(xq.x, w0.x, acc[s].x);                                \
        acc[s].x = fmaf(xq.y, w1.x, acc[s].x);                                \
        acc[s].x = fmaf(xq.z, w2.x, acc[s].x);                                \
        acc[s].x = fmaf(xq.w, w3.x, acc[s].x);                                \
        acc[s].y = fmaf(xq.x, w0.y, acc[s].y);                                \
        acc[s].y = fmaf(xq.y, w1.y, acc[s].y);                                \
        acc[s].y = fmaf(xq.z, w2.y, acc[s].y);                                \
        acc[s].y = fmaf(xq.w, w3.y, acc[s].y);                                \
        acc[s].z = fmaf(xq.x, w0.z, acc[s].z);                                \
        acc[s].z = fmaf(xq.y, w1.z, acc[s].z);                                \
        acc[s].z = fmaf(xq.z, w2.z, acc[s].z);                                \
        acc[s].z = fmaf(xq.w, w3.z, acc[s].z);                                \
        acc[s].w = fmaf(xq.x, w0.w, acc[s].w);                                \
        acc[s].w = fmaf(xq.y, w1.w, acc[s].w);                                \
        acc[s].w = fmaf(xq.z, w2.w, acc[s].w);                                \
        acc[s].w = fmaf(xq.w, w3.w, acc[s].w);                                \
    }                                                                         \
} while (0)

// Reduction helpers: 16 KB region per wave in retired wbuf space.
#define RED_WRITE(region) do {                                                \
    _Pragma("unroll")                                                         \
    for (int s = 0; s < S_CHUNK; ++s)                                         \
        *reinterpret_cast<float4*>(&redbuf[(region) * 4096 + s * 256 + lane * 4]) = acc[s]; \
} while (0)

#define RED_ADD(region) do {                                                  \
    _Pragma("unroll")                                                         \
    for (int s = 0; s < S_CHUNK; ++s) {                                       \
        float4 t_ = *reinterpret_cast<const float4*>(&redbuf[(region) * 4096 + s * 256 + lane * 4]); \
        acc[s].x += t_.x; acc[s].y += t_.y; acc[s].z += t_.z; acc[s].w += t_.w; \
    }                                                                         \
} while (0)

__launch_bounds__(256, 2)
__global__ void k_main(const float* __restrict__ x, const float* __restrict__ kern,
                       const float* __restrict__ bias, const int* __restrict__ order,
                       const int* __restrict__ total_chunks,
                       const int* __restrict__ chunk_cls,
                       const int* __restrict__ chunk_start,
                       const int* __restrict__ chunk_len,
                       float* __restrict__ out) {
    // Runtime-balanced bijective XCD swizzle over active count A = 2*tc.
    int tc = *total_chunks;
    int A  = 2 * tc;
    int xc = blockIdx.x & 7;
    int ii = blockIdx.x >> 3;
    int q  = A >> 3, r = A & 7;
    int mycnt = (xc < r) ? (q + 1) : q;
    if (ii >= mycnt) return;            // block-uniform exit (before barriers)
    int g = ((xc < r) ? xc * (q + 1) : r * (q + 1) + (xc - r) * q) + ii;

    int chunk = g >> 1;
    int ytile = g & 1;

    int tid  = threadIdx.x;
    int lane = tid & 63;
    int wv   = tid >> 6;

    int c     = chunk_cls[chunk];
    int start = chunk_start[chunk];
    int len   = chunk_len[chunk];
    int u0    = ytile * TU;

    __shared__ float wbuf[2][PROWS][TU];   // 32 KB, ring-2, wave-sliced rows
    __shared__ float xs[S_CHUNK][D_DIM];   // 32 KB, shared read-only
    __shared__ int   sidx[S_CHUNK];        // -> 64.3 KB, 2 blocks/CU
    float* redbuf = &wbuf[0][0][0];        // 32 KB scratch for the epilogue

    const float* Wg = kern + (size_t)c * (D_DIM * U_DIM) + u0;

    // ---- prologue ----
    if (tid < S_CHUNK) sidx[tid] = (tid < len) ? order[start + tid] : -1;
    asm volatile("s_waitcnt lgkmcnt(0)" ::: "memory");
    __builtin_amdgcn_s_barrier();          // sidx visible

    // x register loads FIRST (oldest in vm queue), then W pieces 0,1.
    float4 xv[8];
    #pragma unroll
    for (int j = 0; j < 8; ++j) {          // 16 rows x 128 float4 / 256 thr
        int i = tid + 256 * j;
        int s = i >> 7, f = i & 127;
        int b = sidx[s];
        xv[j] = make_float4(0.f, 0.f, 0.f, 0.f);
        if (b >= 0) xv[j] = reinterpret_cast<const float4*>(x)[b * (D_DIM / 4) + f];
    }
    ISSUE(0, 0);                           // 4 instrs/wave
    ISSUE(1, 1);                           // 4 instrs/wave

    asm volatile("s_waitcnt vmcnt(8)" ::: "memory");   // x's 8 drained; W0,W1 in flight
    #pragma unroll
    for (int j = 0; j < 8; ++j) {
        int i = tid + 256 * j;
        int s = i >> 7, f = i & 127;
        reinterpret_cast<float4*>(&xs[s][0])[f] = xv[j];
    }
    asm volatile("s_waitcnt lgkmcnt(0)" ::: "memory");
    __builtin_amdgcn_s_barrier();          // xs visible to all waves — LAST barrier
                                           // before the epilogue reduction.

    float4 acc[S_CHUNK];
    #pragma unroll
    for (int s = 0; s < S_CHUNK; ++s) acc[s] = make_float4(0.f, 0.f, 0.f, 0.f);

    // ---- main loop: 32 pieces, ring-2, ZERO barriers, per-wave vmcnt.
    // Steady state: piece i landed (vmcnt(4) leaves piece i+1's 4 loads in
    // flight), compute my 4 rows x 16 samples, ensure my ds_reads retired
    // (lgkmcnt 0), then refill my slice of buf[i&1] with piece i+2.
    #pragma unroll 1
    for (int i = 0; i < PIECES; ++i) {
        if (i + 1 < PIECES) asm volatile("s_waitcnt vmcnt(4)" ::: "memory");
        else                asm volatile("s_waitcnt vmcnt(0)" ::: "memory");
        COMPUTE(i, (i & 1));
        asm volatile("s_waitcnt lgkmcnt(0)" ::: "memory");  // reads done before overwrite
        if (i + 2 < PIECES) ISSUE(i + 2, (i & 1));
    }

    // ---- epilogue: 4-wave tree reduction of d-partials through LDS ----
    asm volatile("s_waitcnt lgkmcnt(0) vmcnt(0)" ::: "memory");
    __builtin_amdgcn_s_barrier();          // all waves done with wbuf
    if (wv == 2) RED_WRITE(0);
    if (wv == 3) RED_WRITE(1);
    asm volatile("s_waitcnt lgkmcnt(0)" ::: "memory");
    __builtin_amdgcn_s_barrier();
    if (wv == 0) RED_ADD(0);               // acc0 += acc2
    if (wv == 1) RED_ADD(1);               // acc1 += acc3
    asm volatile("s_waitcnt lgkmcnt(0)" ::: "memory");
    __builtin_amdgcn_s_barrier();
    if (wv == 1) RED_WRITE(0);
    asm volatile("s_waitcnt lgkmcnt(0)" ::: "memory");
    __builtin_amdgcn_s_barrier();
    if (wv == 0) {
        RED_ADD(0);                        // acc0 += (acc1+acc3)
        float4 bb = *reinterpret_cast<const float4*>(&bias[c * U_DIM + u0 + lane * 4]);
        #pragma unroll
        for (int s = 0; s < S_CHUNK; ++s) {
            int b = sidx[s];
            if (b >= 0) {
                float4 o = make_float4(acc[s].x + bb.x, acc[s].y + bb.y,
                                       acc[s].z + bb.z, acc[s].w + bb.w);
                *reinterpret_cast<float4*>(&out[(size_t)b * U_DIM + u0 + lane * 4]) = o;
            }
        }
    }
}

// ---------------- launch ----------------

extern "C" void kernel_launch(void* const* d_in, const int* in_sizes, int n_in,
                              void* d_out, int out_size, void* d_ws, size_t ws_size,
                              hipStream_t stream) {
    const float* x    = (const float*)d_in[0];
    const int*   cls  = (const int*)d_in[1];
    const float* kern = (const float*)d_in[2];
    const float* bias = (const float*)d_in[3];
    float*       out  = (float*)d_out;

    int* ws           = (int*)d_ws;
    int* order        = ws;          // 2048
    int* total_chunks = ws + 2048;   // 1
    int* chunk_cls    = ws + 2112;   // 228
    int* chunk_start  = ws + 2368;   // 228
    int* chunk_len    = ws + 2624;   // 228

    hipLaunchKernelGGL(k_sort, dim3(1), dim3(1024), 0, stream,
                       cls, order, total_chunks, chunk_cls, chunk_start, chunk_len);
    hipLaunchKernelGGL(k_main, dim3(NWG), dim3(256), 0, stream,
                       x, kern, bias, order, total_chunks, chunk_cls, chunk_start, chunk_len, out);
}

// Round 13
// 38.760 us; speedup vs baseline: 1.3681x; 1.0595x over previous
//
#include <hip/hip_runtime.h>
#include <hip/hip_bf16.h>

// ConditionalDense: out[b,u] = sum_d x[b,d]*kernel[cls[b],d,u] + bias[cls[b],u]
// B=2048, D=512, U=512, C=100, all float32.
// R13: MFMA formulation on the proven R7 skeleton. Per chunk-ytile block:
// x -> bf16 LDS (once); W pieces (16x256 f32, 16 KB) via global_load_lds
// ring-2 with XOR-swizzled layout (pre-swizzled global source lanes);
// per piece each wave: 4x mfma_f32_16x16x32_bf16 (lower K=16 half used,
// upper B slots zero) covering 16 samples x 64 u x 16 d. f32 accumulate.
// Collapses the f32 path's 256 FMA-instr/wave/piece VALU floor (~10x) and
// cuts LDS read bytes ~4x -- the two invariants across R7..R12's nulls.

typedef __attribute__((ext_vector_type(8))) short bf16x8;
typedef __attribute__((ext_vector_type(4))) short short4v;
typedef __attribute__((ext_vector_type(4))) float floatx4;

constexpr int C_CLS   = 100;
constexpr int B_N     = 2048;
constexpr int D_DIM   = 512;
constexpr int U_DIM   = 512;
constexpr int S_CHUNK = 16;     // samples per chunk = MFMA M
constexpr int MAX_CHUNKS = 228; // >= worst case 2048/16 + 100 = 228
constexpr int TU      = 256;    // u-columns per block (4 waves x 4 n-tiles)
constexpr int PROWS   = 16;     // d-rows per staged W piece (16 KB)
constexpr int PIECES  = D_DIM / PROWS;   // 32
constexpr int NWG     = 2 * MAX_CHUNKS;  // 456

__device__ __forceinline__ short f2bf(float f) {
    return (short)__builtin_bit_cast(unsigned short, __float2bfloat16(f));
}

// ---------------- fused sort kernel (single block, 1024 threads) ----------------

__global__ void k_sort(const int* __restrict__ cls, int* __restrict__ order,
                       int* __restrict__ total_chunks, int* __restrict__ chunk_cls,
                       int* __restrict__ chunk_start, int* __restrict__ chunk_len) {
    __shared__ int s_cnt[128], s_off[128], s_chk[128], s_cur[128], s_base[128];
    int tid = threadIdx.x;
    if (tid < 128) s_cnt[tid] = 0;
    __syncthreads();
    for (int i = tid; i < B_N; i += 1024) atomicAdd(&s_cnt[cls[i]], 1);
    __syncthreads();
    int cnt = 0, nch = 0;
    if (tid < 128) {
        cnt = (tid < C_CLS) ? s_cnt[tid] : 0;
        nch = (cnt + S_CHUNK - 1) / S_CHUNK;
        s_off[tid] = cnt; s_chk[tid] = nch;
    }
    __syncthreads();
    for (int st = 1; st < 128; st <<= 1) {   // Hillis-Steele inclusive scan
        int a = 0, b = 0;
        if (tid >= st && tid < 128) { a = s_off[tid - st]; b = s_chk[tid - st]; }
        __syncthreads();
        if (tid < 128) { s_off[tid] += a; s_chk[tid] += b; }
        __syncthreads();
    }
    if (tid < C_CLS) {
        int off = s_off[tid] - cnt;   // exclusive prefix of counts
        int cb  = s_chk[tid] - nch;   // exclusive prefix of chunk counts
        s_base[tid] = off;
        s_cur[tid]  = 0;
        for (int j = 0; j < nch; ++j) {
            chunk_cls[cb + j]   = tid;
            chunk_start[cb + j] = off + j * S_CHUNK;
            chunk_len[cb + j]   = min(S_CHUNK, cnt - j * S_CHUNK);
        }
    }
    if (tid == 127) *total_chunks = s_chk[127];
    __syncthreads();
    for (int i = tid; i < B_N; i += 1024) {
        int c = cls[i];
        int p = atomicAdd(&s_cur[c], 1);
        order[s_base[c] + p] = i;
    }
}

// ---------------- main kernel ----------------
// Block = (chunk, ytile): 16 samples x 256 u x full D. 256 thr / 4 waves.
// Wave wv owns u-cols [wv*64, wv*64+64) = 4 MFMA n-tiles. Lane: sA=lane&15
// (= A-row/sample and B-col/u-within-tile), g4=lane>>4 (k-group).
// W staged with source-lane swizzle lane^row -> LDS holds byte
// row*1024 + ((col*4)^(row<<4)); readers apply the same XOR -> conflict-free.

#define ISSUE(pi, qq) do {                                                    \
    const int db_ = (pi) * PROWS;                                             \
    _Pragma("unroll")                                                         \
    for (int j_ = 0; j_ < 4; ++j_) {                                          \
        const int r_ = 4 * wv + j_;                                           \
        const float* gp_ = Wg + (size_t)(db_ + r_) * U_DIM + ((lane ^ r_) << 2); \
        __builtin_amdgcn_global_load_lds(                                     \
            (const __attribute__((address_space(1))) void*)gp_,               \
            (__attribute__((address_space(3))) void*)&wbuf[qq][r_][0],        \
            16, 0, 0);                                                        \
    }                                                                         \
} while (0)

#define COMPUTE(pi, qq) do {                                                  \
    const char* xp_ = (const char*)xsb + sA * 1024 +                          \
                      (((pi) * 32 + g4 * 8) ^ sxw_);                          \
    short4v a4 = *reinterpret_cast<const short4v*>(xp_);                      \
    bf16x8 a8;                                                                \
    a8[0] = a4[0]; a8[1] = a4[1]; a8[2] = a4[2]; a8[3] = a4[3];               \
    a8[4] = a4[0]; a8[5] = a4[1]; a8[6] = a4[2]; a8[7] = a4[3];               \
    const char* wb_ = (const char*)wbuf + (qq) * (PROWS * TU * 4);            \
    _Pragma("unroll")                                                         \
    for (int nt = 0; nt < 4; ++nt) {                                          \
        const int cb4_ = ((wv << 6) + nt * 16 + sA) << 2;                     \
        bf16x8 b8;                                                            \
        _Pragma("unroll")                                                     \
        for (int j_ = 0; j_ < 4; ++j_) {                                      \
            const int rl_ = g4 * 4 + j_;                                      \
            float w_ = *reinterpret_cast<const float*>(                       \
                wb_ + rl_ * 1024 + (cb4_ ^ (rl_ << 4)));                      \
            b8[j_] = f2bf(w_);                                                \
        }                                                                     \
        b8[4] = 0; b8[5] = 0; b8[6] = 0; b8[7] = 0;                           \
        acc[nt] = __builtin_amdgcn_mfma_f32_16x16x32_bf16(a8, b8, acc[nt], 0, 0, 0); \
    }                                                                         \
} while (0)

__launch_bounds__(256, 2)
__global__ void k_main(const float* __restrict__ x, const float* __restrict__ kern,
                       const float* __restrict__ bias, const int* __restrict__ order,
                       const int* __restrict__ total_chunks,
                       const int* __restrict__ chunk_cls,
                       const int* __restrict__ chunk_start,
                       const int* __restrict__ chunk_len,
                       float* __restrict__ out) {
    // Runtime-balanced bijective XCD swizzle over active count A = 2*tc.
    int tc = *total_chunks;
    int A  = 2 * tc;
    int xc = blockIdx.x & 7;
    int ii = blockIdx.x >> 3;
    int q  = A >> 3, r = A & 7;
    int mycnt = (xc < r) ? (q + 1) : q;
    if (ii >= mycnt) return;            // block-uniform exit (before barriers)
    int g = ((xc < r) ? xc * (q + 1) : r * (q + 1) + (xc - r) * q) + ii;

    int chunk = g >> 1;
    int ytile = g & 1;

    int tid  = threadIdx.x;
    int lane = tid & 63;
    int wv   = tid >> 6;
    int sA   = lane & 15;
    int g4   = lane >> 4;
    const int sxw_ = (sA & 7) << 4;     // xsb row-XOR for this lane's A-row

    int c     = chunk_cls[chunk];
    int start = chunk_start[chunk];
    int len   = chunk_len[chunk];
    int u0    = ytile * TU;

    __shared__ float          wbuf[2][PROWS][TU];   // 32 KB, ring-2, swizzled
    __shared__ unsigned short xsb[S_CHUNK][D_DIM];  // 16 KB bf16, swizzled
    __shared__ int            sidx[S_CHUNK];        // -> 48.2 KB, 3 blk/CU

    const float* Wg = kern + (size_t)c * (D_DIM * U_DIM) + u0;

    // ---- prologue ----
    if (tid < S_CHUNK) sidx[tid] = (tid < len) ? order[start + tid] : -1;
    asm volatile("s_waitcnt lgkmcnt(0)" ::: "memory");
    __builtin_amdgcn_s_barrier();          // sidx visible

    // x: thread t handles row srow = t>>4, cols [cb, cb+32) contiguous.
    int srow = tid >> 4;
    int cb   = (tid & 15) * 32;
    int bsmp = sidx[srow]; if (bsmp < 0) bsmp = sidx[0];   // pad: junk row, never stored
    float4 xv[8];
    #pragma unroll
    for (int j = 0; j < 8; ++j)
        xv[j] = reinterpret_cast<const float4*>(x + (size_t)bsmp * D_DIM + cb)[j];

    ISSUE(0, 0);                           // W pieces 0,1 behind the x loads
    ISSUE(1, 1);
    asm volatile("s_waitcnt vmcnt(8)" ::: "memory");   // x's 8 done; W's 8 in flight

    {   // convert 32 f32 -> bf16, write 4 swizzled 16-B chunks
        char* xrow = (char*)xsb + srow * 1024;
        int   swz  = (srow & 7) << 4;
        #pragma unroll
        for (int m = 0; m < 4; ++m) {
            bf16x8 pk;
            pk[0] = f2bf(xv[2*m].x);   pk[1] = f2bf(xv[2*m].y);
            pk[2] = f2bf(xv[2*m].z);   pk[3] = f2bf(xv[2*m].w);
            pk[4] = f2bf(xv[2*m+1].x); pk[5] = f2bf(xv[2*m+1].y);
            pk[6] = f2bf(xv[2*m+1].z); pk[7] = f2bf(xv[2*m+1].w);
            *reinterpret_cast<bf16x8*>(xrow + ((cb * 2 + m * 16) ^ swz)) = pk;
        }
    }
    asm volatile("s_waitcnt lgkmcnt(0)" ::: "memory");
    __builtin_amdgcn_s_barrier();          // xsb visible; pipeline primed

    floatx4 acc[4];
    #pragma unroll
    for (int k = 0; k < 4; ++k) acc[k] = (floatx4){0.f, 0.f, 0.f, 0.f};

    // ---- main loop: 32 pieces, ring-2, R7 cadence ----
    #pragma unroll 1
    for (int i = 0; i < PIECES; ++i) {
        if (i + 1 < PIECES) asm volatile("s_waitcnt vmcnt(4)" ::: "memory");
        else                asm volatile("s_waitcnt vmcnt(0)" ::: "memory");
        __builtin_amdgcn_s_barrier();      // piece i fully in LDS (all waves)
        COMPUTE(i, (i & 1));
        asm volatile("" ::: "memory");     // keep LDS reads above barrier 2
        __builtin_amdgcn_s_barrier();      // all waves done reading buf[i&1]
        if (i + 2 < PIECES) ISSUE(i + 2, (i & 1));
    }

    // ---- epilogue: D[row=g4*4+r][col=sA] per n-tile; direct stores ----
    #pragma unroll
    for (int nt = 0; nt < 4; ++nt) {
        int u = u0 + (wv << 6) + nt * 16 + sA;
        float bb = bias[c * U_DIM + u];
        #pragma unroll
        for (int r2 = 0; r2 < 4; ++r2) {
            int b = sidx[g4 * 4 + r2];
            if (b >= 0) out[(size_t)b * U_DIM + u] = acc[nt][r2] + bb;
        }
    }
}

// ---------------- launch ----------------

extern "C" void kernel_launch(void* const* d_in, const int* in_sizes, int n_in,
                              void* d_out, int out_size, void* d_ws, size_t ws_size,
                              hipStream_t stream) {
    const float* x    = (const float*)d_in[0];
    const int*   cls  = (const int*)d_in[1];
    const float* kern = (const float*)d_in[2];
    const float* bias = (const float*)d_in[3];
    float*       out  = (float*)d_out;

    int* ws           = (int*)d_ws;
    int* order        = ws;          // 2048
    int* total_chunks = ws + 2048;   // 1
    int* chunk_cls    = ws + 2112;   // 228
    int* chunk_start  = ws + 2368;   // 228
    int* chunk_len    = ws + 2624;   // 228

    hipLaunchKernelGGL(k_sort, dim3(1), dim3(1024), 0, stream,
                       cls, order, total_chunks, chunk_cls, chunk_start, chunk_len);
    hipLaunchKernelGGL(k_main, dim3(NWG), dim3(256), 0, stream,
                       x, kern, bias, order, total_chunks, chunk_cls, chunk_start, chunk_len, out);
}

// Round 14
// 32.409 us; speedup vs baseline: 1.6362x; 1.1959x over previous
//
#include <hip/hip_runtime.h>
#include <hip/hip_bf16.h>

// ConditionalDense: out[b,u] = sum_d x[b,d]*kernel[cls[b],d,u] + bias[cls[b],u]
// B=2048, D=512, U=512, C=100, all float32.
// R14 = R13's MFMA structure with the logical-traffic cut S_CHUNK=32:
// chunks ~190 -> ~101, logical W 190 MB -> ~101 MB (= unique floor).
// Enabled by bf16 xs (32 samples = 32 KB): S=32 x TU=128 x ring-4 of
// 8 KB W pieces = 64.4 KB LDS -> 2 blk/CU, ~404 active blocks, 3 pieces
// (24 KB/block) in flight. Per wave per piece: 2 m-tiles x 2 n-tiles
// mfma_f32_16x16x32_bf16 (lower K=16 half; upper B slots zero).
// Prior S=32 failures were confounds: R4 = 1 blk/CU, R5 = atomics+DF.

typedef __attribute__((ext_vector_type(8))) short bf16x8;
typedef __attribute__((ext_vector_type(4))) short short4v;
typedef __attribute__((ext_vector_type(4))) float floatx4;

constexpr int C_CLS   = 100;
constexpr int B_N     = 2048;
constexpr int D_DIM   = 512;
constexpr int U_DIM   = 512;
constexpr int S_CHUNK = 32;     // samples per chunk = 2 MFMA m-tiles
constexpr int MAX_CHUNKS = 164; // >= worst case (2048+100*31)/32 = 161
constexpr int TU      = 128;    // u-columns per block (4 waves x 2 n-tiles)
constexpr int PROWS   = 16;     // d-rows per staged W piece (8 KB)
constexpr int PIECES  = D_DIM / PROWS;   // 32
constexpr int NQ      = 4;      // W ring depth (3 pieces in flight)
constexpr int NWG     = 4 * MAX_CHUNKS;  // 656 = 8*82

__device__ __forceinline__ short f2bf(float f) {
    return (short)__builtin_bit_cast(unsigned short, __float2bfloat16(f));
}

// ---------------- fused sort kernel (single block, 1024 threads) ----------------

__global__ void k_sort(const int* __restrict__ cls, int* __restrict__ order,
                       int* __restrict__ total_chunks, int* __restrict__ chunk_cls,
                       int* __restrict__ chunk_start, int* __restrict__ chunk_len) {
    __shared__ int s_cnt[128], s_off[128], s_chk[128], s_cur[128], s_base[128];
    int tid = threadIdx.x;
    if (tid < 128) s_cnt[tid] = 0;
    __syncthreads();
    for (int i = tid; i < B_N; i += 1024) atomicAdd(&s_cnt[cls[i]], 1);
    __syncthreads();
    int cnt = 0, nch = 0;
    if (tid < 128) {
        cnt = (tid < C_CLS) ? s_cnt[tid] : 0;
        nch = (cnt + S_CHUNK - 1) / S_CHUNK;
        s_off[tid] = cnt; s_chk[tid] = nch;
    }
    __syncthreads();
    for (int st = 1; st < 128; st <<= 1) {   // Hillis-Steele inclusive scan
        int a = 0, b = 0;
        if (tid >= st && tid < 128) { a = s_off[tid - st]; b = s_chk[tid - st]; }
        __syncthreads();
        if (tid < 128) { s_off[tid] += a; s_chk[tid] += b; }
        __syncthreads();
    }
    if (tid < C_CLS) {
        int off = s_off[tid] - cnt;   // exclusive prefix of counts
        int cb  = s_chk[tid] - nch;   // exclusive prefix of chunk counts
        s_base[tid] = off;
        s_cur[tid]  = 0;
        for (int j = 0; j < nch; ++j) {
            chunk_cls[cb + j]   = tid;
            chunk_start[cb + j] = off + j * S_CHUNK;
            chunk_len[cb + j]   = min(S_CHUNK, cnt - j * S_CHUNK);
        }
    }
    if (tid == 127) *total_chunks = s_chk[127];
    __syncthreads();
    for (int i = tid; i < B_N; i += 1024) {
        int c = cls[i];
        int p = atomicAdd(&s_cur[c], 1);
        order[s_base[c] + p] = i;
    }
}

// ---------------- main kernel ----------------
// Block = (chunk, ytile): 32 samples x 128 u x full D=512. 256 thr/4 waves.
// Wave wv owns u [wv*32, wv*32+32) = 2 n-tiles; m-tiles = samples 0-15,16-31.
// Lane: sA = lane&15 (A-row within m-tile = B-col within n-tile),
// g4 = lane>>4 (k-group; also C-row group). W pieces: 16 rows x 128 f32 =
// 8 KB, ring-4, XOR-swizzled (both sides: pre-swizzled global source quads,
// same XOR on LDS reads; dword bits 2-5 ^ (row&15)).

#define ISSUE(pi, qq) do {                                                    \
    const int db_ = (pi) * PROWS;                                             \
    _Pragma("unroll")                                                         \
    for (int j_ = 0; j_ < 2; ++j_) {                                          \
        const int r_  = wv * 4 + 2 * j_;      /* wave-uniform base row */     \
        const int rr_ = r_ + (lane >> 5);     /* per-lane row (r_, r_+1) */   \
        const float* gp_ = Wg + (size_t)(db_ + rr_) * U_DIM                   \
                           + (((lane & 31) ^ (rr_ & 15)) << 2);               \
        __builtin_amdgcn_global_load_lds(                                     \
            (const __attribute__((address_space(1))) void*)gp_,               \
            (__attribute__((address_space(3))) void*)&wbuf[qq][r_][0],        \
            16, 0, 0);                                                        \
    }                                                                         \
} while (0)

#define COMPUTE(pi, qq) do {                                                  \
    bf16x8 a8_0, a8_1;                                                        \
    {                                                                         \
        const int xb_ = ((pi) * 32 + g4 * 8) ^ sxw_;                          \
        short4v a4 = *reinterpret_cast<const short4v*>(                       \
            (const char*)xsb + sA * 1024 + xb_);                              \
        a8_0[0]=a4[0]; a8_0[1]=a4[1]; a8_0[2]=a4[2]; a8_0[3]=a4[3];           \
        a8_0[4]=a4[0]; a8_0[5]=a4[1]; a8_0[6]=a4[2]; a8_0[7]=a4[3];           \
        short4v a4b = *reinterpret_cast<const short4v*>(                      \
            (const char*)xsb + (16 + sA) * 1024 + xb_);                       \
        a8_1[0]=a4b[0]; a8_1[1]=a4b[1]; a8_1[2]=a4b[2]; a8_1[3]=a4b[3];       \
        a8_1[4]=a4b[0]; a8_1[5]=a4b[1]; a8_1[6]=a4b[2]; a8_1[7]=a4b[3];       \
    }                                                                         \
    const char* wb_ = (const char*)wbuf + (qq) * (PROWS * TU * 4);            \
    _Pragma("unroll")                                                         \
    for (int nt = 0; nt < 2; ++nt) {                                          \
        const int cb4_ = ((wv << 5) + nt * 16 + sA) << 2;                     \
        bf16x8 b8;                                                            \
        _Pragma("unroll")                                                     \
        for (int j_ = 0; j_ < 4; ++j_) {                                      \
            const int rl_ = g4 * 4 + j_;                                      \
            float w_ = *reinterpret_cast<const float*>(                       \
                wb_ + rl_ * 512 + (cb4_ ^ (rl_ << 4)));                       \
            b8[j_] = f2bf(w_);                                                \
        }                                                                     \
        b8[4] = 0; b8[5] = 0; b8[6] = 0; b8[7] = 0;                           \
        acc0[nt] = __builtin_amdgcn_mfma_f32_16x16x32_bf16(a8_0, b8, acc0[nt], 0, 0, 0); \
        acc1[nt] = __builtin_amdgcn_mfma_f32_16x16x32_bf16(a8_1, b8, acc1[nt], 0, 0, 0); \
    }                                                                         \
} while (0)

#define STEP(pi, NCNT) do {                                                   \
    asm volatile("s_waitcnt vmcnt(" #NCNT ")" ::: "memory");                  \
    __builtin_amdgcn_s_barrier();          /* piece pi fully in LDS */        \
    COMPUTE(pi, (pi) & 3);                                                    \
    asm volatile("" ::: "memory");                                            \
    __builtin_amdgcn_s_barrier();          /* all waves done with slot */     \
    if ((pi) + NQ < PIECES) ISSUE((pi) + NQ, (pi) & 3);                       \
} while (0)

__launch_bounds__(256, 2)
__global__ void k_main(const float* __restrict__ x, const float* __restrict__ kern,
                       const float* __restrict__ bias, const int* __restrict__ order,
                       const int* __restrict__ total_chunks,
                       const int* __restrict__ chunk_cls,
                       const int* __restrict__ chunk_start,
                       const int* __restrict__ chunk_len,
                       float* __restrict__ out) {
    // Runtime-balanced bijective XCD swizzle over active count A = 4*tc.
    int tc = *total_chunks;
    int A  = 4 * tc;
    int xc = blockIdx.x & 7;
    int ii = blockIdx.x >> 3;
    int q  = A >> 3, r = A & 7;
    int mycnt = (xc < r) ? (q + 1) : q;
    if (ii >= mycnt) return;            // block-uniform exit (before barriers)
    int g = ((xc < r) ? xc * (q + 1) : r * (q + 1) + (xc - r) * q) + ii;

    int chunk = g >> 2;
    int ytile = g & 3;

    int tid  = threadIdx.x;
    int lane = tid & 63;
    int wv   = tid >> 6;
    int sA   = lane & 15;
    int g4   = lane >> 4;
    const int sxw_ = (sA & 7) << 4;     // xsb row-XOR (rows sA and 16+sA share it)

    int c     = chunk_cls[chunk];
    int start = chunk_start[chunk];
    int len   = chunk_len[chunk];
    int u0    = ytile * TU;

    __shared__ float          wbuf[NQ][PROWS][TU];  // 32 KB, ring-4, swizzled
    __shared__ unsigned short xsb[S_CHUNK][D_DIM];  // 32 KB bf16, swizzled
    __shared__ int            sidx[S_CHUNK];        // -> 64.4 KB, 2 blk/CU

    const float* Wg = kern + (size_t)c * (D_DIM * U_DIM) + u0;

    // ---- prologue ----
    if (tid < S_CHUNK) sidx[tid] = (tid < len) ? order[start + tid] : -1;
    asm volatile("s_waitcnt lgkmcnt(0)" ::: "memory");
    __builtin_amdgcn_s_barrier();          // sidx visible

    // x: 2 passes; pass p: thread handles row p*16 + (tid>>4), 32 cols.
    float4 xv0[8], xv1[8];
    int srow0 = (tid >> 4), srow1 = 16 + (tid >> 4);
    int cb    = (tid & 15) * 32;
    {
        int b0 = sidx[srow0]; if (b0 < 0) b0 = sidx[0];
        int b1 = sidx[srow1]; if (b1 < 0) b1 = sidx[0];
        #pragma unroll
        for (int j = 0; j < 8; ++j)
            xv0[j] = reinterpret_cast<const float4*>(x + (size_t)b0 * D_DIM + cb)[j];
        #pragma unroll
        for (int j = 0; j < 8; ++j)
            xv1[j] = reinterpret_cast<const float4*>(x + (size_t)b1 * D_DIM + cb)[j];
    }
    ISSUE(0, 0);                           // W pieces 0..3 behind the x loads
    ISSUE(1, 1);
    ISSUE(2, 2);
    ISSUE(3, 3);
    asm volatile("s_waitcnt vmcnt(8)" ::: "memory");   // x's 16 done; W's 8 fly

    {   // convert f32 -> bf16, write swizzled 16-B chunks
        #pragma unroll
        for (int p = 0; p < 2; ++p) {
            int   row  = p ? srow1 : srow0;
            char* xrow = (char*)xsb + row * 1024;
            int   swz  = (row & 7) << 4;
            #pragma unroll
            for (int m = 0; m < 4; ++m) {
                float4 va = p ? xv1[2*m]     : xv0[2*m];
                float4 vb = p ? xv1[2*m + 1] : xv0[2*m + 1];
                bf16x8 pk;
                pk[0] = f2bf(va.x); pk[1] = f2bf(va.y);
                pk[2] = f2bf(va.z); pk[3] = f2bf(va.w);
                pk[4] = f2bf(vb.x); pk[5] = f2bf(vb.y);
                pk[6] = f2bf(vb.z); pk[7] = f2bf(vb.w);
                *reinterpret_cast<bf16x8*>(xrow + ((cb * 2 + m * 16) ^ swz)) = pk;
            }
        }
    }
    asm volatile("s_waitcnt lgkmcnt(0)" ::: "memory");
    __builtin_amdgcn_s_barrier();          // xsb visible; pipeline primed

    floatx4 acc0[2], acc1[2];
    #pragma unroll
    for (int k = 0; k < 2; ++k) {
        acc0[k] = (floatx4){0.f, 0.f, 0.f, 0.f};
        acc1[k] = (floatx4){0.f, 0.f, 0.f, 0.f};
    }

    // ---- main loop: 32 pieces, ring-4, steady vmcnt(6) = 3 pieces in flight ----
    #pragma unroll 1
    for (int i = 0; i <= 27; ++i) STEP(i, 6);
    STEP(28, 6);                           // pieces 29,30,31 outstanding
    STEP(29, 4);
    STEP(30, 2);
    STEP(31, 0);

    // ---- epilogue: direct stores, one writer per output element ----
    #pragma unroll
    for (int mt = 0; mt < 2; ++mt) {
        #pragma unroll
        for (int nt = 0; nt < 2; ++nt) {
            int u  = u0 + (wv << 5) + nt * 16 + sA;
            float bb = bias[c * U_DIM + u];
            floatx4 a = mt ? acc1[nt] : acc0[nt];
            #pragma unroll
            for (int r2 = 0; r2 < 4; ++r2) {
                int b = sidx[mt * 16 + g4 * 4 + r2];
                if (b >= 0) out[(size_t)b * U_DIM + u] = a[r2] + bb;
            }
        }
    }
}

// ---------------- launch ----------------

extern "C" void kernel_launch(void* const* d_in, const int* in_sizes, int n_in,
                              void* d_out, int out_size, void* d_ws, size_t ws_size,
                              hipStream_t stream) {
    const float* x    = (const float*)d_in[0];
    const int*   cls  = (const int*)d_in[1];
    const float* kern = (const float*)d_in[2];
    const float* bias = (const float*)d_in[3];
    float*       out  = (float*)d_out;

    int* ws           = (int*)d_ws;
    int* order        = ws;          // 2048
    int* total_chunks = ws + 2048;   // 1
    int* chunk_cls    = ws + 2112;   // 164
    int* chunk_start  = ws + 2304;   // 164
    int* chunk_len    = ws + 2496;   // 164

    hipLaunchKernelGGL(k_sort, dim3(1), dim3(1024), 0, stream,
                       cls, order, total_chunks, chunk_cls, chunk_start, chunk_len);
    hipLaunchKernelGGL(k_main, dim3(NWG), dim3(256), 0, stream,
                       x, kern, bias, order, total_chunks, chunk_cls, chunk_start, chunk_len, out);
}